// Round 3
// baseline (536.488 us; speedup 1.0000x reference)
//
#include <hip/hip_runtime.h>
#include <hip/hip_bf16.h>
#include <cstdint>
#include <cstddef>

#define NTOK 8192
#define DMODEL 1024
#define DFF 4096
#define NEXP 8
#define CAP 2048

typedef __attribute__((ext_vector_type(8))) __bf16 bf16x8;
typedef __attribute__((ext_vector_type(4))) float f32x4;

__device__ __forceinline__ void gload16(const void* g, void* l) {
  __builtin_amdgcn_global_load_lds(
      (__attribute__((address_space(1))) void*)(g),
      (__attribute__((address_space(3))) void*)(l),
      16, 0, 0);
}
#define VMWAIT(n) asm volatile("s_waitcnt vmcnt(" #n ")" ::: "memory")

__global__ __launch_bounds__(256) void zero_f32(float* p, int n4) {
  int i = blockIdx.x * blockDim.x + threadIdx.x;
  int stride = gridDim.x * blockDim.x;
  float4 z = make_float4(0.f, 0.f, 0.f, 0.f);
  for (; i < n4; i += stride) ((float4*)p)[i] = z;
}

__global__ __launch_bounds__(256) void router_kernel(
    const float* __restrict__ x, const float* __restrict__ Wr,
    float* __restrict__ scoresT, __hip_bfloat16* __restrict__ xb) {
  const int lane = threadIdx.x & 63;
  const int t = blockIdx.x * 4 + (threadIdx.x >> 6);
  const float* xr = x + (size_t)t * DMODEL;
  float acc[NEXP];
#pragma unroll
  for (int j = 0; j < NEXP; ++j) acc[j] = 0.f;
#pragma unroll
  for (int it = 0; it < DMODEL / 64; ++it) {
    int d = it * 64 + lane;
    float xv = xr[d];
    xb[(size_t)t * DMODEL + d] = __float2bfloat16(xv);
    const float4* w = (const float4*)(Wr + (size_t)d * NEXP);
    float4 w0 = w[0], w1 = w[1];
    acc[0] += xv * w0.x; acc[1] += xv * w0.y; acc[2] += xv * w0.z; acc[3] += xv * w0.w;
    acc[4] += xv * w1.x; acc[5] += xv * w1.y; acc[6] += xv * w1.z; acc[7] += xv * w1.w;
  }
#pragma unroll
  for (int off = 32; off; off >>= 1) {
#pragma unroll
    for (int j = 0; j < NEXP; ++j) acc[j] += __shfl_xor(acc[j], off);
  }
  float m = acc[0];
#pragma unroll
  for (int j = 1; j < NEXP; ++j) m = fmaxf(m, acc[j]);
  float s = 0.f;
#pragma unroll
  for (int j = 0; j < NEXP; ++j) { acc[j] = expf(acc[j] - m); s += acc[j]; }
  float inv = 1.f / s;
  if (lane < NEXP) scoresT[(size_t)lane * NTOK + t] = acc[lane] * inv;
}

__global__ __launch_bounds__(256) void topk_kernel(
    const float* __restrict__ scoresT, float* __restrict__ G, int* __restrict__ IDX) {
  __shared__ uint32_t sb[NTOK];
  __shared__ uint32_t hist[256];
  __shared__ uint32_t s_prefix, s_rem;
  __shared__ uint32_t eq_list[256];
  __shared__ uint32_t eq_cnt, gt_cnt;
  const int e = blockIdx.x, tid = threadIdx.x;
  const float* se = scoresT + (size_t)e * NTOK;
  for (int i = tid; i < NTOK; i += 256) sb[i] = __float_as_uint(se[i]);
  if (tid == 0) { s_prefix = 0u; s_rem = CAP; eq_cnt = 0u; gt_cnt = 0u; }
  __syncthreads();
  for (int r = 0; r < 4; ++r) {
    const int shift = 24 - 8 * r;
    for (int i = tid; i < 256; i += 256) hist[i] = 0u;
    __syncthreads();
    uint32_t pfx = s_prefix;
    for (int i = tid; i < NTOK; i += 256) {
      uint32_t b = sb[i];
      if (((b >> shift) >> 8) == pfx) atomicAdd(&hist[(b >> shift) & 255u], 1u);
    }
    __syncthreads();
    if (tid == 0) {
      uint32_t rem = s_rem, cum = 0u;
      int d = 255;
      for (; d > 0; --d) {
        if (cum + hist[d] >= rem) break;
        cum += hist[d];
      }
      s_prefix = (pfx << 8) | (uint32_t)d;
      s_rem = rem - cum;
    }
    __syncthreads();
  }
  const uint32_t T = s_prefix, need = s_rem;
  for (int i = tid; i < NTOK; i += 256) {
    uint32_t b = sb[i];
    if (b > T) {
      uint32_t p = atomicAdd(&gt_cnt, 1u);
      IDX[(size_t)e * CAP + p] = i;
      G[(size_t)e * CAP + p] = __uint_as_float(b);
    } else if (b == T) {
      uint32_t c = atomicAdd(&eq_cnt, 1u);
      if (c < 256u) eq_list[c] = (uint32_t)i;
    }
  }
  __syncthreads();
  if (tid == 0) {
    uint32_t base = gt_cnt;
    uint32_t c = eq_cnt < 256u ? eq_cnt : 256u;
    for (uint32_t s = 0; s < need; ++s) {
      uint32_t mv = 0xFFFFFFFFu; int mi = 0;
      for (uint32_t j = 0; j < c; ++j)
        if (eq_list[j] < mv) { mv = eq_list[j]; mi = (int)j; }
      eq_list[mi] = 0xFFFFFFFFu;
      IDX[(size_t)e * CAP + base + s] = (int)mv;
      G[(size_t)e * CAP + base + s] = __uint_as_float(T);
    }
  }
}

__global__ __launch_bounds__(256) void transpose_cvt(
    const float* __restrict__ in, __hip_bfloat16* __restrict__ out, int R, int C) {
  __shared__ float tile[32][33];
  const int e = blockIdx.z;
  const float* ine = in + (size_t)e * R * C;
  __hip_bfloat16* oute = out + (size_t)e * R * C;
  const int c0 = blockIdx.x * 32, r0 = blockIdx.y * 32;
  const int tx = threadIdx.x, ty = threadIdx.y;
#pragma unroll
  for (int i = 0; i < 4; ++i)
    tile[ty + i * 8][tx] = ine[(size_t)(r0 + ty + i * 8) * C + (c0 + tx)];
  __syncthreads();
#pragma unroll
  for (int i = 0; i < 4; ++i)
    oute[(size_t)(c0 + ty + i * 8) * R + (r0 + tx)] =
        __float2bfloat16(tile[tx][ty + i * 8]);
}

// ---------------- 256x256 deep-pipelined GEMMs, 4-phase per K-tile ----------
// BK=32, 4-deep LDS ring (128 KiB), 8 waves (2M x 4N), per-wave 128x64 output.
// Per K-tile: vmcnt gate (counted, never 0 mid-loop) + barrier; then 4 phases:
// {ds_read 2 A-frags (+4 B-frags at p0); 1 stage gload (tile t+3, dead slot);
//  s_barrier; lgkmcnt(0)+sched_barrier; setprio(1); 8 MFMA; setprio(0);
//  trailing s_barrier (p<3; loop-top barrier covers p3)}.
// Quarter swizzle q' = (q + (row>>1))&3 on pre-swizzled global src + ds_read.

template <int NT>
__device__ __forceinline__ void gemm_core(
    const char* srcA0, const char* srcA1, const char* srcB0, const char* srcB1,
    int ldsA0, int ldsA1, int ldsB0, int ldsB1,
    const int* offA, const int* offB, char* smem, f32x4 (&acc)[8][4]) {
  const char* sA[2] = {srcA0, srcA1};
  const char* sB[2] = {srcB0, srcB1};
  int lA[2] = {ldsA0, ldsA1};
  int lB[2] = {ldsB0, ldsB1};
#pragma unroll
  for (int t = 0; t < 3; ++t) {
    char* base = smem + t * 32768;
#pragma unroll
    for (int j = 0; j < 2; ++j) {
      gload16(sA[j], base + lA[j]); sA[j] += 64;
      gload16(sB[j], base + lB[j]); sB[j] += 64;
    }
  }
  for (int t = 0; t < NT; ++t) {
    if (t < NT - 2) { VMWAIT(8); }
    else if (t == NT - 2) { VMWAIT(4); }
    else { VMWAIT(0); }
    __builtin_amdgcn_s_barrier();
    asm volatile("" ::: "memory");
    const char* base = smem + (t & 3) * 32768;
    char* sbase = smem + ((t + 3) & 3) * 32768;
    const bool dostage = (t < NT - 3);
    bf16x8 bfr[4];
#pragma unroll
    for (int p = 0; p < 4; ++p) {
      bf16x8 a0 = *(const bf16x8*)(base + offA[2 * p]);
      bf16x8 a1 = *(const bf16x8*)(base + offA[2 * p + 1]);
      if (p == 0) {
#pragma unroll
        for (int ni = 0; ni < 4; ++ni)
          bfr[ni] = *(const bf16x8*)(base + offB[ni]);
      }
      if (dostage) {
        if (p == 0)      { gload16(sA[0], sbase + lA[0]); sA[0] += 64; }
        else if (p == 1) { gload16(sA[1], sbase + lA[1]); sA[1] += 64; }
        else if (p == 2) { gload16(sB[0], sbase + lB[0]); sB[0] += 64; }
        else             { gload16(sB[1], sbase + lB[1]); sB[1] += 64; }
      }
      __builtin_amdgcn_s_barrier();
      asm volatile("s_waitcnt lgkmcnt(0)" ::: "memory");
      __builtin_amdgcn_sched_barrier(0);
      __builtin_amdgcn_s_setprio(1);
#pragma unroll
      for (int ni = 0; ni < 4; ++ni) {
        acc[2 * p][ni] = __builtin_amdgcn_mfma_f32_16x16x32_bf16(
            a0, bfr[ni], acc[2 * p][ni], 0, 0, 0);
        acc[2 * p + 1][ni] = __builtin_amdgcn_mfma_f32_16x16x32_bf16(
            a1, bfr[ni], acc[2 * p + 1][ni], 0, 0, 0);
      }
      __builtin_amdgcn_s_setprio(0);
      if (p < 3) __builtin_amdgcn_s_barrier();
    }
  }
}

__global__ __launch_bounds__(512, 2) void gemm1_kernel(
    const __hip_bfloat16* __restrict__ xb,
    const __hip_bfloat16* __restrict__ W1t,
    const float* __restrict__ b1,
    const int* __restrict__ IDX,
    __hip_bfloat16* __restrict__ h, int e0, int nblk) {
  __shared__ __align__(16) char smem[131072];
  int lin = blockIdx.x;
  { int q = nblk >> 3; lin = (lin & 7) * q + (lin >> 3); }  // XCD-contiguous
  const int tm = lin & 7, tn = (lin >> 3) & 15, ez = lin >> 7;
  const int e = e0 + ez;
  const int tid = threadIdx.x, wave = tid >> 6, lane = tid & 63;
  const int wm = wave >> 2, wn = wave & 3;
  const int lrow = lane & 15, lgrp = lane >> 4;

  const char* srcA[2]; const char* srcB[2];
  int lA[2], lB[2];
#pragma unroll
  for (int j = 0; j < 2; ++j) {
    int chunk = j * 8 + wave;
    int slot = chunk * 64 + lane;
    int r = slot >> 2, qp = slot & 3;
    int q = (qp - (r >> 1)) & 3;
    lA[j] = chunk * 1024;
    lB[j] = 16384 + chunk * 1024;
    int tok = IDX[e * CAP + tm * 256 + r];
    srcA[j] = (const char*)(xb + (size_t)tok * DMODEL + q * 8);
    srcB[j] = (const char*)(W1t + ((size_t)e * DFF + tn * 256 + r) * DMODEL + q * 8);
  }
  int offA[8], offB[4];
#pragma unroll
  for (int mi = 0; mi < 8; ++mi) {
    int rr = wm * 128 + mi * 16 + lrow;
    offA[mi] = rr * 64 + ((lgrp + (rr >> 1)) & 3) * 16;
  }
#pragma unroll
  for (int ni = 0; ni < 4; ++ni) {
    int rr = wn * 64 + ni * 16 + lrow;
    offB[ni] = 16384 + rr * 64 + ((lgrp + (rr >> 1)) & 3) * 16;
  }
  f32x4 acc[8][4];
  f32x4 zero = {0.f, 0.f, 0.f, 0.f};
#pragma unroll
  for (int mi = 0; mi < 8; ++mi)
#pragma unroll
    for (int ni = 0; ni < 4; ++ni) acc[mi][ni] = zero;

  gemm_core<DMODEL / 32>(srcA[0], srcA[1], srcB[0], srcB[1],
                         lA[0], lA[1], lB[0], lB[1], offA, offB, smem, acc);

  __hip_bfloat16* he = h + (size_t)ez * CAP * DFF;
  const float* b1e = b1 + (size_t)e * DFF;
  float bvals[4];
#pragma unroll
  for (int ni = 0; ni < 4; ++ni)
    bvals[ni] = b1e[tn * 256 + wn * 64 + ni * 16 + lrow];
#pragma unroll
  for (int mi = 0; mi < 8; ++mi) {
#pragma unroll
    for (int j = 0; j < 4; ++j) {
      int row = tm * 256 + wm * 128 + mi * 16 + lgrp * 4 + j;
      __hip_bfloat16* hrow = he + (size_t)row * DFF;
#pragma unroll
      for (int ni = 0; ni < 4; ++ni) {
        int col = tn * 256 + wn * 64 + ni * 16 + lrow;
        float v = acc[mi][ni][j] + bvals[ni];
        v = 0.5f * v * (1.f + erff(v * 0.70710678118654752f));
        hrow[col] = __float2bfloat16(v);
      }
    }
  }
}

__global__ __launch_bounds__(512, 2) void gemm2_kernel(
    const __hip_bfloat16* __restrict__ h,
    const __hip_bfloat16* __restrict__ W2t,
    const float* __restrict__ b2,
    const int* __restrict__ IDX, const float* __restrict__ G,
    float* __restrict__ out, int e0, int nblk) {
  __shared__ __align__(16) char smem[131072];
  int lin = blockIdx.x;
  { int q = nblk >> 3; lin = (lin & 7) * q + (lin >> 3); }
  const int tm = lin & 7, tn = (lin >> 3) & 3, ez = lin >> 5;
  const int e = e0 + ez;
  const int tid = threadIdx.x, wave = tid >> 6, lane = tid & 63;
  const int wm = wave >> 2, wn = wave & 3;
  const int lrow = lane & 15, lgrp = lane >> 4;

  const char* srcA[2]; const char* srcB[2];
  int lA[2], lB[2];
#pragma unroll
  for (int j = 0; j < 2; ++j) {
    int chunk = j * 8 + wave;
    int slot = chunk * 64 + lane;
    int r = slot >> 2, qp = slot & 3;
    int q = (qp - (r >> 1)) & 3;
    lA[j] = chunk * 1024;
    lB[j] = 16384 + chunk * 1024;
    srcA[j] = (const char*)(h + ((size_t)ez * CAP + tm * 256 + r) * DFF + q * 8);
    srcB[j] = (const char*)(W2t + ((size_t)e * DMODEL + tn * 256 + r) * DFF + q * 8);
  }
  int offA[8], offB[4];
#pragma unroll
  for (int mi = 0; mi < 8; ++mi) {
    int rr = wm * 128 + mi * 16 + lrow;
    offA[mi] = rr * 64 + ((lgrp + (rr >> 1)) & 3) * 16;
  }
#pragma unroll
  for (int ni = 0; ni < 4; ++ni) {
    int rr = wn * 64 + ni * 16 + lrow;
    offB[ni] = 16384 + rr * 64 + ((lgrp + (rr >> 1)) & 3) * 16;
  }
  f32x4 acc[8][4];
  f32x4 zero = {0.f, 0.f, 0.f, 0.f};
#pragma unroll
  for (int mi = 0; mi < 8; ++mi)
#pragma unroll
    for (int ni = 0; ni < 4; ++ni) acc[mi][ni] = zero;

  gemm_core<DFF / 32>(srcA[0], srcA[1], srcB[0], srcB[1],
                      lA[0], lA[1], lB[0], lB[1], offA, offB, smem, acc);

  const float* b2e = b2 + (size_t)e * DMODEL;
  const int* idxe = IDX + (size_t)e * CAP;
  const float* ge = G + (size_t)e * CAP;
  float bvals[4];
#pragma unroll
  for (int ni = 0; ni < 4; ++ni)
    bvals[ni] = b2e[tn * 256 + wn * 64 + ni * 16 + lrow];
#pragma unroll
  for (int mi = 0; mi < 8; ++mi) {
#pragma unroll
    for (int j = 0; j < 4; ++j) {
      int row = tm * 256 + wm * 128 + mi * 16 + lgrp * 4 + j;
      float g = ge[row];
      int tok = idxe[row];
      float* orow = out + (size_t)tok * DMODEL;
#pragma unroll
      for (int ni = 0; ni < 4; ++ni) {
        int col = tn * 256 + wn * 64 + ni * 16 + lrow;
        atomicAdd(orow + col, (acc[mi][ni][j] + bvals[ni]) * g);
      }
    }
  }
}

extern "C" void kernel_launch(void* const* d_in, const int* in_sizes, int n_in,
                              void* d_out, int out_size, void* d_ws, size_t ws_size,
                              hipStream_t stream) {
  const float* x  = (const float*)d_in[0];
  const float* Wr = (const float*)d_in[1];
  const float* W1 = (const float*)d_in[2];
  const float* b1 = (const float*)d_in[3];
  const float* W2 = (const float*)d_in[4];
  const float* b2 = (const float*)d_in[5];
  float* out = (float*)d_out;
  char* ws = (char*)d_ws;

  size_t off = 0;
  float* scoresT = (float*)(ws + off); off += (size_t)NEXP * NTOK * 4;
  float* G       = (float*)(ws + off); off += (size_t)NEXP * CAP * 4;
  int*   IDX     = (int*)(ws + off);   off += (size_t)NEXP * CAP * 4;
  __hip_bfloat16* xb  = (__hip_bfloat16*)(ws + off); off += (size_t)NTOK * DMODEL * 2;
  __hip_bfloat16* W1t = (__hip_bfloat16*)(ws + off); off += (size_t)NEXP * DFF * DMODEL * 2;
  __hip_bfloat16* W2t = (__hip_bfloat16*)(ws + off); off += (size_t)NEXP * DMODEL * DFF * 2;
  __hip_bfloat16* hbuf = (__hip_bfloat16*)(ws + off);
  size_t h_per_e = (size_t)CAP * DFF * 2;
  size_t avail = (ws_size > off) ? (ws_size - off) : 0;
  int EC = (int)(avail / h_per_e);
  if (EC < 1) EC = 1;
  if (EC > NEXP) EC = NEXP;

  zero_f32<<<512, 256, 0, stream>>>(out, out_size / 4);
  router_kernel<<<NTOK / 4, 256, 0, stream>>>(x, Wr, scoresT, xb);
  topk_kernel<<<NEXP, 256, 0, stream>>>(scoresT, G, IDX);
  transpose_cvt<<<dim3(DFF / 32, DMODEL / 32, NEXP), dim3(32, 8), 0, stream>>>(
      W1, W1t, DMODEL, DFF);
  transpose_cvt<<<dim3(DMODEL / 32, DFF / 32, NEXP), dim3(32, 8), 0, stream>>>(
      W2, W2t, DFF, DMODEL);
  for (int e0 = 0; e0 < NEXP; e0 += EC) {
    int ne = (NEXP - e0 < EC) ? (NEXP - e0) : EC;
    int nblk1 = 128 * ne;
    gemm1_kernel<<<nblk1, 512, 0, stream>>>(xb, W1t, b1, IDX, hbuf, e0, nblk1);
    int nblk2 = 32 * ne;
    gemm2_kernel<<<nblk2, 512, 0, stream>>>(hbuf, W2t, b2, IDX, G, out, e0, nblk2);
  }
}

// Round 4
// 499.299 us; speedup vs baseline: 1.0745x; 1.0745x over previous
//
#include <hip/hip_runtime.h>
#include <hip/hip_bf16.h>
#include <cstdint>
#include <cstddef>

#define NTOK 8192
#define DMODEL 1024
#define DFF 4096
#define NEXP 8
#define CAP 2048

typedef __attribute__((ext_vector_type(8))) __bf16 bf16x8;
typedef __attribute__((ext_vector_type(4))) float f32x4;

__device__ __forceinline__ void gload16(const void* g, void* l) {
  __builtin_amdgcn_global_load_lds(
      (__attribute__((address_space(1))) void*)(g),
      (__attribute__((address_space(3))) void*)(l),
      16, 0, 0);
}
#define VMWAIT_(n) asm volatile("s_waitcnt vmcnt(" #n ")" ::: "memory")
#define VMWAIT(n) VMWAIT_(n)
#define MEMFENCE asm volatile("" ::: "memory")

__global__ __launch_bounds__(256) void zero_f32(float* p, int n4) {
  int i = blockIdx.x * blockDim.x + threadIdx.x;
  int stride = gridDim.x * blockDim.x;
  float4 z = make_float4(0.f, 0.f, 0.f, 0.f);
  for (; i < n4; i += stride) ((float4*)p)[i] = z;
}

__global__ __launch_bounds__(256) void router_kernel(
    const float* __restrict__ x, const float* __restrict__ Wr,
    float* __restrict__ scoresT, __hip_bfloat16* __restrict__ xb) {
  const int lane = threadIdx.x & 63;
  const int t = blockIdx.x * 4 + (threadIdx.x >> 6);
  const float* xr = x + (size_t)t * DMODEL;
  float acc[NEXP];
#pragma unroll
  for (int j = 0; j < NEXP; ++j) acc[j] = 0.f;
#pragma unroll
  for (int it = 0; it < DMODEL / 64; ++it) {
    int d = it * 64 + lane;
    float xv = xr[d];
    xb[(size_t)t * DMODEL + d] = __float2bfloat16(xv);
    const float4* w = (const float4*)(Wr + (size_t)d * NEXP);
    float4 w0 = w[0], w1 = w[1];
    acc[0] += xv * w0.x; acc[1] += xv * w0.y; acc[2] += xv * w0.z; acc[3] += xv * w0.w;
    acc[4] += xv * w1.x; acc[5] += xv * w1.y; acc[6] += xv * w1.z; acc[7] += xv * w1.w;
  }
#pragma unroll
  for (int off = 32; off; off >>= 1) {
#pragma unroll
    for (int j = 0; j < NEXP; ++j) acc[j] += __shfl_xor(acc[j], off);
  }
  float m = acc[0];
#pragma unroll
  for (int j = 1; j < NEXP; ++j) m = fmaxf(m, acc[j]);
  float s = 0.f;
#pragma unroll
  for (int j = 0; j < NEXP; ++j) { acc[j] = expf(acc[j] - m); s += acc[j]; }
  float inv = 1.f / s;
  if (lane < NEXP) scoresT[(size_t)lane * NTOK + t] = acc[lane] * inv;
}

__global__ __launch_bounds__(256) void topk_kernel(
    const float* __restrict__ scoresT, float* __restrict__ G, int* __restrict__ IDX) {
  __shared__ uint32_t sb[NTOK];
  __shared__ uint32_t hist[256];
  __shared__ uint32_t s_prefix, s_rem;
  __shared__ uint32_t eq_list[256];
  __shared__ uint32_t eq_cnt, gt_cnt;
  const int e = blockIdx.x, tid = threadIdx.x;
  const float* se = scoresT + (size_t)e * NTOK;
  for (int i = tid; i < NTOK; i += 256) sb[i] = __float_as_uint(se[i]);
  if (tid == 0) { s_prefix = 0u; s_rem = CAP; eq_cnt = 0u; gt_cnt = 0u; }
  __syncthreads();
  for (int r = 0; r < 4; ++r) {
    const int shift = 24 - 8 * r;
    for (int i = tid; i < 256; i += 256) hist[i] = 0u;
    __syncthreads();
    uint32_t pfx = s_prefix;
    for (int i = tid; i < NTOK; i += 256) {
      uint32_t b = sb[i];
      if (((b >> shift) >> 8) == pfx) atomicAdd(&hist[(b >> shift) & 255u], 1u);
    }
    __syncthreads();
    if (tid == 0) {
      uint32_t rem = s_rem, cum = 0u;
      int d = 255;
      for (; d > 0; --d) {
        if (cum + hist[d] >= rem) break;
        cum += hist[d];
      }
      s_prefix = (pfx << 8) | (uint32_t)d;
      s_rem = rem - cum;
    }
    __syncthreads();
  }
  const uint32_t T = s_prefix, need = s_rem;
  for (int i = tid; i < NTOK; i += 256) {
    uint32_t b = sb[i];
    if (b > T) {
      uint32_t p = atomicAdd(&gt_cnt, 1u);
      IDX[(size_t)e * CAP + p] = i;
      G[(size_t)e * CAP + p] = __uint_as_float(b);
    } else if (b == T) {
      uint32_t c = atomicAdd(&eq_cnt, 1u);
      if (c < 256u) eq_list[c] = (uint32_t)i;
    }
  }
  __syncthreads();
  if (tid == 0) {
    uint32_t base = gt_cnt;
    uint32_t c = eq_cnt < 256u ? eq_cnt : 256u;
    for (uint32_t s = 0; s < need; ++s) {
      uint32_t mv = 0xFFFFFFFFu; int mi = 0;
      for (uint32_t j = 0; j < c; ++j)
        if (eq_list[j] < mv) { mv = eq_list[j]; mi = (int)j; }
      eq_list[mi] = 0xFFFFFFFFu;
      IDX[(size_t)e * CAP + base + s] = (int)mv;
      G[(size_t)e * CAP + base + s] = __uint_as_float(T);
    }
  }
}

__global__ __launch_bounds__(256) void transpose_cvt(
    const float* __restrict__ in, __hip_bfloat16* __restrict__ out, int R, int C) {
  __shared__ float tile[32][33];
  const int e = blockIdx.z;
  const float* ine = in + (size_t)e * R * C;
  __hip_bfloat16* oute = out + (size_t)e * R * C;
  const int c0 = blockIdx.x * 32, r0 = blockIdx.y * 32;
  const int tx = threadIdx.x, ty = threadIdx.y;
#pragma unroll
  for (int i = 0; i < 4; ++i)
    tile[ty + i * 8][tx] = ine[(size_t)(r0 + ty + i * 8) * C + (c0 + tx)];
  __syncthreads();
#pragma unroll
  for (int i = 0; i < 4; ++i)
    oute[(size_t)(c0 + ty + i * 8) * R + (r0 + tx)] =
        __float2bfloat16(tile[tx][ty + i * 8]);
}

// ============ 256x256, BK=64, m201-grain 4-phase-per-K-tile pipeline ========
// LDS: 2 K-tile buffers x 4 pieces x 16KB = 128 KiB.
// Pieces: A-h0 (m-frags 0-3 rows of both wm halves), A-h1 (m-frags 4-7),
//         B-h0 (n-frags 0-1 cols of all wn quarters), B-h1 (n-frags 2-3).
// Piece-local row rr: A: m = (rr>>6)*128 + h*64 + (rr&63)
//                     B: n = (rr>>5)*64  + h*32 + (rr&31)
// Swizzle: 16B slot s stored at phys slot (s + rr) & 7 within the 128B row.
// Per K-tile: 4 phases {vmcnt(4); bar; ds_reads; stage 1 piece of kt+1;
//   bar; lgkmcnt(0); setprio(1); 16 MFMA; setprio(0)}; stage order A0,B0,B1,A1.

template <int NKT>
__device__ __forceinline__ void gemm_core8(
    const char* a00, const char* a01, const char* a10, const char* a11,
    const char* b00, const char* b01, const char* b10, const char* b11,
    char* smem, f32x4 (&acc)[8][4]) {
  const int tid = threadIdx.x;
  const int wave = tid >> 6, lane = tid & 63;
  const int wm = wave >> 2, wn = wave & 3;
  const int lrow = lane & 15, lgrp = lane >> 4;
  const int dst = tid * 16;

  int offA[8][2], offB[4][2];
#pragma unroll
  for (int mi = 0; mi < 8; ++mi) {
    int rL = wm * 64 + (mi & 3) * 16 + lrow;
    int pbase = (mi >> 2) * 16384;
#pragma unroll
    for (int ks = 0; ks < 2; ++ks)
      offA[mi][ks] = pbase + rL * 128 + (((ks * 4 + lgrp + rL) & 7) << 4);
  }
#pragma unroll
  for (int ni = 0; ni < 4; ++ni) {
    int rL = wn * 32 + (ni & 1) * 16 + lrow;
    int pbase = 32768 + (ni >> 1) * 16384;
#pragma unroll
    for (int ks = 0; ks < 2; ++ks)
      offB[ni][ks] = pbase + rL * 128 + (((ks * 4 + lgrp + rL) & 7) << 4);
  }
  const char* pa[2][2] = {{a00, a01}, {a10, a11}};
  const char* pb[2][2] = {{b00, b01}, {b10, b11}};

  // prologue: stage kt0 into buf0 (order A0, B0, B1, A1)
  {
    char* sb = smem;
    gload16(pa[0][0], sb + dst);          gload16(pa[0][1], sb + 8192 + dst);
    pa[0][0] += 128; pa[0][1] += 128;
    gload16(pb[0][0], sb + 32768 + dst);  gload16(pb[0][1], sb + 40960 + dst);
    pb[0][0] += 128; pb[0][1] += 128;
    gload16(pb[1][0], sb + 49152 + dst);  gload16(pb[1][1], sb + 57344 + dst);
    pb[1][0] += 128; pb[1][1] += 128;
    gload16(pa[1][0], sb + 16384 + dst);  gload16(pa[1][1], sb + 24576 + dst);
    pa[1][0] += 128; pa[1][1] += 128;
  }
  bf16x8 av[4][2], b0v[2][2], b1v[2][2];

  for (int kt = 0; kt < NKT; ++kt) {
    char* buf = smem + ((kt & 1) << 16);
    char* sb  = smem + (((kt + 1) & 1) << 16);
    const bool st = (kt < NKT - 1);
    const bool last = (kt == NKT - 1);

    // ---- phase 0: A-h0 + B-h0 reads; MFMA quadrant (mi0-3 x ni0-1)
    VMWAIT(4);
    __builtin_amdgcn_s_barrier();
    MEMFENCE;
#pragma unroll
    for (int mi = 0; mi < 4; ++mi)
#pragma unroll
      for (int ks = 0; ks < 2; ++ks)
        av[mi][ks] = *(const bf16x8*)(buf + offA[mi][ks]);
#pragma unroll
    for (int ni = 0; ni < 2; ++ni)
#pragma unroll
      for (int ks = 0; ks < 2; ++ks)
        b0v[ni][ks] = *(const bf16x8*)(buf + offB[ni][ks]);
    if (st) {
      gload16(pa[0][0], sb + dst); gload16(pa[0][1], sb + 8192 + dst);
      pa[0][0] += 128; pa[0][1] += 128;
    }
    __builtin_amdgcn_s_barrier();
    asm volatile("s_waitcnt lgkmcnt(0)" ::: "memory");
    __builtin_amdgcn_s_setprio(1);
#pragma unroll
    for (int mi = 0; mi < 4; ++mi)
#pragma unroll
      for (int ni = 0; ni < 2; ++ni)
#pragma unroll
        for (int ks = 0; ks < 2; ++ks)
          acc[mi][ni] = __builtin_amdgcn_mfma_f32_16x16x32_bf16(
              av[mi][ks], b0v[ni][ks], acc[mi][ni], 0, 0, 0);
    __builtin_amdgcn_s_setprio(0);

    // ---- phase 1: B-h1 reads; MFMA (mi0-3 x ni2-3)
    if (last) { VMWAIT(2); } else { VMWAIT(4); }
    __builtin_amdgcn_s_barrier();
    MEMFENCE;
#pragma unroll
    for (int ni = 0; ni < 2; ++ni)
#pragma unroll
      for (int ks = 0; ks < 2; ++ks)
        b1v[ni][ks] = *(const bf16x8*)(buf + offB[2 + ni][ks]);
    if (st) {
      gload16(pb[0][0], sb + 32768 + dst); gload16(pb[0][1], sb + 40960 + dst);
      pb[0][0] += 128; pb[0][1] += 128;
    }
    __builtin_amdgcn_s_barrier();
    asm volatile("s_waitcnt lgkmcnt(0)" ::: "memory");
    __builtin_amdgcn_s_setprio(1);
#pragma unroll
    for (int mi = 0; mi < 4; ++mi)
#pragma unroll
      for (int ni = 0; ni < 2; ++ni)
#pragma unroll
        for (int ks = 0; ks < 2; ++ks)
          acc[mi][2 + ni] = __builtin_amdgcn_mfma_f32_16x16x32_bf16(
              av[mi][ks], b1v[ni][ks], acc[mi][2 + ni], 0, 0, 0);
    __builtin_amdgcn_s_setprio(0);

    // ---- phase 2: A-h1 reads; MFMA (mi4-7 x ni2-3)
    if (last) { VMWAIT(0); } else { VMWAIT(4); }
    __builtin_amdgcn_s_barrier();
    MEMFENCE;
#pragma unroll
    for (int mi = 0; mi < 4; ++mi)
#pragma unroll
      for (int ks = 0; ks < 2; ++ks)
        av[mi][ks] = *(const bf16x8*)(buf + offA[4 + mi][ks]);
    if (st) {
      gload16(pb[1][0], sb + 49152 + dst); gload16(pb[1][1], sb + 57344 + dst);
      pb[1][0] += 128; pb[1][1] += 128;
    }
    __builtin_amdgcn_s_barrier();
    asm volatile("s_waitcnt lgkmcnt(0)" ::: "memory");
    __builtin_amdgcn_s_setprio(1);
#pragma unroll
    for (int mi = 0; mi < 4; ++mi)
#pragma unroll
      for (int ni = 0; ni < 2; ++ni)
#pragma unroll
        for (int ks = 0; ks < 2; ++ks)
          acc[4 + mi][2 + ni] = __builtin_amdgcn_mfma_f32_16x16x32_bf16(
              av[mi][ks], b1v[ni][ks], acc[4 + mi][2 + ni], 0, 0, 0);
    __builtin_amdgcn_s_setprio(0);

    // ---- phase 3: no reads (b0v live); MFMA (mi4-7 x ni0-1)
    if (st) {
      gload16(pa[1][0], sb + 16384 + dst); gload16(pa[1][1], sb + 24576 + dst);
      pa[1][0] += 128; pa[1][1] += 128;
    }
    __builtin_amdgcn_s_barrier();
    __builtin_amdgcn_s_setprio(1);
#pragma unroll
    for (int mi = 0; mi < 4; ++mi)
#pragma unroll
      for (int ni = 0; ni < 2; ++ni)
#pragma unroll
        for (int ks = 0; ks < 2; ++ks)
          acc[4 + mi][ni] = __builtin_amdgcn_mfma_f32_16x16x32_bf16(
              av[mi][ks], b0v[ni][ks], acc[4 + mi][ni], 0, 0, 0);
    __builtin_amdgcn_s_setprio(0);
  }
}

__global__ __launch_bounds__(512, 2) void gemm1_kernel(
    const __hip_bfloat16* __restrict__ xb,
    const __hip_bfloat16* __restrict__ W1t,
    const float* __restrict__ b1,
    const int* __restrict__ IDX,
    __hip_bfloat16* __restrict__ h, int e0, int nblk) {
  __shared__ __align__(16) char smem[131072];
  int lin = blockIdx.x;
  { int q = nblk >> 3; lin = (lin & 7) * q + (lin >> 3); }  // XCD-contiguous
  const int tm = lin & 7, tn = (lin >> 3) & 15, ez = lin >> 7;
  const int e = e0 + ez;
  const int tid = threadIdx.x, wave = tid >> 6, lane = tid & 63;
  const int wm = wave >> 2, wn = wave & 3;
  const int lrow = lane & 15, lgrp = lane >> 4;

  const int r0 = tid >> 3;
  const int s16 = (((tid & 7) - r0) & 7) * 16;
  const char* srcA[2][2]; const char* srcB[2][2];
#pragma unroll
  for (int hh = 0; hh < 2; ++hh)
#pragma unroll
    for (int j = 0; j < 2; ++j) {
      int m = j * 128 + hh * 64 + r0;
      int tok = IDX[e * CAP + tm * 256 + m];
      srcA[hh][j] = (const char*)(xb + (size_t)tok * DMODEL) + s16;
      int n = j * 128 + (r0 >> 5) * 64 + hh * 32 + (r0 & 31);
      srcB[hh][j] = (const char*)(W1t + ((size_t)e * DFF + tn * 256 + n) * DMODEL) + s16;
    }

  f32x4 acc[8][4];
  f32x4 zero = {0.f, 0.f, 0.f, 0.f};
#pragma unroll
  for (int mi = 0; mi < 8; ++mi)
#pragma unroll
    for (int ni = 0; ni < 4; ++ni) acc[mi][ni] = zero;

  gemm_core8<DMODEL / 64>(srcA[0][0], srcA[0][1], srcA[1][0], srcA[1][1],
                          srcB[0][0], srcB[0][1], srcB[1][0], srcB[1][1],
                          smem, acc);

  __hip_bfloat16* he = h + (size_t)ez * CAP * DFF;
  const float* b1e = b1 + (size_t)e * DFF;
  float bvals[4];
#pragma unroll
  for (int ni = 0; ni < 4; ++ni)
    bvals[ni] = b1e[tn * 256 + wn * 64 + ni * 16 + lrow];
#pragma unroll
  for (int mi = 0; mi < 8; ++mi) {
#pragma unroll
    for (int j = 0; j < 4; ++j) {
      int row = tm * 256 + wm * 128 + mi * 16 + lgrp * 4 + j;
      __hip_bfloat16* hrow = he + (size_t)row * DFF;
#pragma unroll
      for (int ni = 0; ni < 4; ++ni) {
        int col = tn * 256 + wn * 64 + ni * 16 + lrow;
        float v = acc[mi][ni][j] + bvals[ni];
        v = 0.5f * v * (1.f + erff(v * 0.70710678118654752f));
        hrow[col] = __float2bfloat16(v);
      }
    }
  }
}

__global__ __launch_bounds__(512, 2) void gemm2_kernel(
    const __hip_bfloat16* __restrict__ h,
    const __hip_bfloat16* __restrict__ W2t,
    const float* __restrict__ b2,
    const int* __restrict__ IDX, const float* __restrict__ G,
    float* __restrict__ out, int e0, int nblk) {
  __shared__ __align__(16) char smem[131072];
  int lin = blockIdx.x;
  { int q = nblk >> 3; lin = (lin & 7) * q + (lin >> 3); }
  const int tm = lin & 7, tn = (lin >> 3) & 3, ez = lin >> 5;
  const int e = e0 + ez;
  const int tid = threadIdx.x, wave = tid >> 6, lane = tid & 63;
  const int wm = wave >> 2, wn = wave & 3;
  const int lrow = lane & 15, lgrp = lane >> 4;

  const int r0 = tid >> 3;
  const int s16 = (((tid & 7) - r0) & 7) * 16;
  const char* srcA[2][2]; const char* srcB[2][2];
#pragma unroll
  for (int hh = 0; hh < 2; ++hh)
#pragma unroll
    for (int j = 0; j < 2; ++j) {
      int m = j * 128 + hh * 64 + r0;
      srcA[hh][j] = (const char*)(h + ((size_t)ez * CAP + tm * 256 + m) * DFF) + s16;
      int n = j * 128 + (r0 >> 5) * 64 + hh * 32 + (r0 & 31);
      srcB[hh][j] = (const char*)(W2t + ((size_t)e * DMODEL + tn * 256 + n) * DFF) + s16;
    }

  f32x4 acc[8][4];
  f32x4 zero = {0.f, 0.f, 0.f, 0.f};
#pragma unroll
  for (int mi = 0; mi < 8; ++mi)
#pragma unroll
    for (int ni = 0; ni < 4; ++ni) acc[mi][ni] = zero;

  gemm_core8<DFF / 64>(srcA[0][0], srcA[0][1], srcA[1][0], srcA[1][1],
                       srcB[0][0], srcB[0][1], srcB[1][0], srcB[1][1],
                       smem, acc);

  const float* b2e = b2 + (size_t)e * DMODEL;
  const int* idxe = IDX + (size_t)e * CAP;
  const float* ge = G + (size_t)e * CAP;
  float bvals[4];
#pragma unroll
  for (int ni = 0; ni < 4; ++ni)
    bvals[ni] = b2e[tn * 256 + wn * 64 + ni * 16 + lrow];
#pragma unroll
  for (int mi = 0; mi < 8; ++mi) {
#pragma unroll
    for (int j = 0; j < 4; ++j) {
      int row = tm * 256 + wm * 128 + mi * 16 + lgrp * 4 + j;
      float g = ge[row];
      int tok = idxe[row];
      float* orow = out + (size_t)tok * DMODEL;
#pragma unroll
      for (int ni = 0; ni < 4; ++ni) {
        int col = tn * 256 + wn * 64 + ni * 16 + lrow;
        atomicAdd(orow + col, (acc[mi][ni][j] + bvals[ni]) * g);
      }
    }
  }
}

extern "C" void kernel_launch(void* const* d_in, const int* in_sizes, int n_in,
                              void* d_out, int out_size, void* d_ws, size_t ws_size,
                              hipStream_t stream) {
  const float* x  = (const float*)d_in[0];
  const float* Wr = (const float*)d_in[1];
  const float* W1 = (const float*)d_in[2];
  const float* b1 = (const float*)d_in[3];
  const float* W2 = (const float*)d_in[4];
  const float* b2 = (const float*)d_in[5];
  float* out = (float*)d_out;
  char* ws = (char*)d_ws;

  size_t off = 0;
  float* scoresT = (float*)(ws + off); off += (size_t)NEXP * NTOK * 4;
  float* G       = (float*)(ws + off); off += (size_t)NEXP * CAP * 4;
  int*   IDX     = (int*)(ws + off);   off += (size_t)NEXP * CAP * 4;
  __hip_bfloat16* xb  = (__hip_bfloat16*)(ws + off); off += (size_t)NTOK * DMODEL * 2;
  __hip_bfloat16* W1t = (__hip_bfloat16*)(ws + off); off += (size_t)NEXP * DFF * DMODEL * 2;
  __hip_bfloat16* W2t = (__hip_bfloat16*)(ws + off); off += (size_t)NEXP * DMODEL * DFF * 2;
  __hip_bfloat16* hbuf = (__hip_bfloat16*)(ws + off);
  size_t h_per_e = (size_t)CAP * DFF * 2;
  size_t avail = (ws_size > off) ? (ws_size - off) : 0;
  int EC = (int)(avail / h_per_e);
  if (EC < 1) EC = 1;
  if (EC > NEXP) EC = NEXP;

  zero_f32<<<512, 256, 0, stream>>>(out, out_size / 4);
  router_kernel<<<NTOK / 4, 256, 0, stream>>>(x, Wr, scoresT, xb);
  topk_kernel<<<NEXP, 256, 0, stream>>>(scoresT, G, IDX);
  transpose_cvt<<<dim3(DFF / 32, DMODEL / 32, NEXP), dim3(32, 8), 0, stream>>>(
      W1, W1t, DMODEL, DFF);
  transpose_cvt<<<dim3(DMODEL / 32, DFF / 32, NEXP), dim3(32, 8), 0, stream>>>(
      W2, W2t, DFF, DMODEL);
  for (int e0 = 0; e0 < NEXP; e0 += EC) {
    int ne = (NEXP - e0 < EC) ? (NEXP - e0) : EC;
    int nblk1 = 128 * ne;
    gemm1_kernel<<<nblk1, 512, 0, stream>>>(xb, W1t, b1, IDX, hbuf, e0, nblk1);
    int nblk2 = 32 * ne;
    gemm2_kernel<<<nblk2, 512, 0, stream>>>(hbuf, W2t, b2, IDX, G, out, e0, nblk2);
  }
}

// Round 5
// 475.665 us; speedup vs baseline: 1.1279x; 1.0497x over previous
//
#include <hip/hip_runtime.h>
#include <hip/hip_bf16.h>
#include <cstdint>
#include <cstddef>

#define NTOK 8192
#define DMODEL 1024
#define DFF 4096
#define NEXP 8
#define CAP 2048

typedef __attribute__((ext_vector_type(8))) __bf16 bf16x8;
typedef __attribute__((ext_vector_type(4))) float f32x4;

__device__ __forceinline__ void gload16(const void* g, void* l) {
  __builtin_amdgcn_global_load_lds(
      (__attribute__((address_space(1))) void*)(g),
      (__attribute__((address_space(3))) void*)(l),
      16, 0, 0);
}
#define VMWAIT_(n) asm volatile("s_waitcnt vmcnt(" #n ")" ::: "memory")
#define VMWAIT(n) VMWAIT_(n)
#define MEMFENCE asm volatile("" ::: "memory")

__global__ __launch_bounds__(256) void zero_f32(float* p, int n4) {
  int i = blockIdx.x * blockDim.x + threadIdx.x;
  int stride = gridDim.x * blockDim.x;
  float4 z = make_float4(0.f, 0.f, 0.f, 0.f);
  for (; i < n4; i += stride) ((float4*)p)[i] = z;
}

__global__ __launch_bounds__(256) void router_kernel(
    const float* __restrict__ x, const float* __restrict__ Wr,
    float* __restrict__ scoresT, __hip_bfloat16* __restrict__ xb) {
  const int lane = threadIdx.x & 63;
  const int t = blockIdx.x * 4 + (threadIdx.x >> 6);
  const float* xr = x + (size_t)t * DMODEL;
  float acc[NEXP];
#pragma unroll
  for (int j = 0; j < NEXP; ++j) acc[j] = 0.f;
#pragma unroll
  for (int it = 0; it < DMODEL / 64; ++it) {
    int d = it * 64 + lane;
    float xv = xr[d];
    xb[(size_t)t * DMODEL + d] = __float2bfloat16(xv);
    const float4* w = (const float4*)(Wr + (size_t)d * NEXP);
    float4 w0 = w[0], w1 = w[1];
    acc[0] += xv * w0.x; acc[1] += xv * w0.y; acc[2] += xv * w0.z; acc[3] += xv * w0.w;
    acc[4] += xv * w1.x; acc[5] += xv * w1.y; acc[6] += xv * w1.z; acc[7] += xv * w1.w;
  }
#pragma unroll
  for (int off = 32; off; off >>= 1) {
#pragma unroll
    for (int j = 0; j < NEXP; ++j) acc[j] += __shfl_xor(acc[j], off);
  }
  float m = acc[0];
#pragma unroll
  for (int j = 1; j < NEXP; ++j) m = fmaxf(m, acc[j]);
  float s = 0.f;
#pragma unroll
  for (int j = 0; j < NEXP; ++j) { acc[j] = expf(acc[j] - m); s += acc[j]; }
  float inv = 1.f / s;
  if (lane < NEXP) scoresT[(size_t)lane * NTOK + t] = acc[lane] * inv;
}

__global__ __launch_bounds__(256) void topk_kernel(
    const float* __restrict__ scoresT, float* __restrict__ G, int* __restrict__ IDX) {
  __shared__ uint32_t sb[NTOK];
  __shared__ uint32_t hist[256];
  __shared__ uint32_t s_prefix, s_rem;
  __shared__ uint32_t eq_list[256];
  __shared__ uint32_t eq_cnt, gt_cnt;
  const int e = blockIdx.x, tid = threadIdx.x;
  const float* se = scoresT + (size_t)e * NTOK;
  for (int i = tid; i < NTOK; i += 256) sb[i] = __float_as_uint(se[i]);
  if (tid == 0) { s_prefix = 0u; s_rem = CAP; eq_cnt = 0u; gt_cnt = 0u; }
  __syncthreads();
  for (int r = 0; r < 4; ++r) {
    const int shift = 24 - 8 * r;
    for (int i = tid; i < 256; i += 256) hist[i] = 0u;
    __syncthreads();
    uint32_t pfx = s_prefix;
    for (int i = tid; i < NTOK; i += 256) {
      uint32_t b = sb[i];
      if (((b >> shift) >> 8) == pfx) atomicAdd(&hist[(b >> shift) & 255u], 1u);
    }
    __syncthreads();
    if (tid == 0) {
      uint32_t rem = s_rem, cum = 0u;
      int d = 255;
      for (; d > 0; --d) {
        if (cum + hist[d] >= rem) break;
        cum += hist[d];
      }
      s_prefix = (pfx << 8) | (uint32_t)d;
      s_rem = rem - cum;
    }
    __syncthreads();
  }
  const uint32_t T = s_prefix, need = s_rem;
  for (int i = tid; i < NTOK; i += 256) {
    uint32_t b = sb[i];
    if (b > T) {
      uint32_t p = atomicAdd(&gt_cnt, 1u);
      IDX[(size_t)e * CAP + p] = i;
      G[(size_t)e * CAP + p] = __uint_as_float(b);
    } else if (b == T) {
      uint32_t c = atomicAdd(&eq_cnt, 1u);
      if (c < 256u) eq_list[c] = (uint32_t)i;
    }
  }
  __syncthreads();
  if (tid == 0) {
    uint32_t base = gt_cnt;
    uint32_t c = eq_cnt < 256u ? eq_cnt : 256u;
    for (uint32_t s = 0; s < need; ++s) {
      uint32_t mv = 0xFFFFFFFFu; int mi = 0;
      for (uint32_t j = 0; j < c; ++j)
        if (eq_list[j] < mv) { mv = eq_list[j]; mi = (int)j; }
      eq_list[mi] = 0xFFFFFFFFu;
      IDX[(size_t)e * CAP + base + s] = (int)mv;
      G[(size_t)e * CAP + base + s] = __uint_as_float(T);
    }
  }
}

__global__ __launch_bounds__(256) void transpose_cvt(
    const float* __restrict__ in, __hip_bfloat16* __restrict__ out, int R, int C) {
  __shared__ float tile[32][33];
  const int e = blockIdx.z;
  const float* ine = in + (size_t)e * R * C;
  __hip_bfloat16* oute = out + (size_t)e * R * C;
  const int c0 = blockIdx.x * 32, r0 = blockIdx.y * 32;
  const int tx = threadIdx.x, ty = threadIdx.y;
#pragma unroll
  for (int i = 0; i < 4; ++i)
    tile[ty + i * 8][tx] = ine[(size_t)(r0 + ty + i * 8) * C + (c0 + tx)];
  __syncthreads();
#pragma unroll
  for (int i = 0; i < 4; ++i)
    oute[(size_t)(c0 + ty + i * 8) * R + (r0 + tx)] =
        __float2bfloat16(tile[tx][ty + i * 8]);
}

// ======== 256x256, BK=64, depth-2 counted-vmcnt pipeline (m218 principle) ====
// LDS: 2 K-tile buffers x 64 KB (A 32KB rows[256][64k] + B 32KB rows[256][64k]).
// Row swizzle: 16B slot s of row r stored at phys slot (s+r)&7 (inverse-rotated
// global source; both-sides-or-neither per G21).  Per K-tile kt:
//   vmcnt(8) [kt's 8 loads were issued at kt-2 => ~2 K-tiles of latency cover;
//             the 8 outstanding are kt+1's]  + barrier
//   12 ds_read_b128 (ks0 frags) -> 32 MFMA   (setprio wrapped)
//   12 ds_read_b128 (ks1 frags) -> lgkmcnt(0) -> barrier  [buffer fully read]
//   stage kt+2 into this same buffer (8 global_load_lds) -> sched_barrier
//   32 MFMA (ks1)
// 2 barriers + 1 counted vmcnt per K-tile; vmcnt never drains mid-loop.

template <int NKT>
__device__ __forceinline__ void gemm_core_v5(
    const char* pa0, const char* pa1, const char* pa2, const char* pa3,
    const char* pb0, const char* pb1, const char* pb2, const char* pb3,
    char* smem, f32x4 (&acc)[8][4]) {
  const int tid = threadIdx.x;
  const int wave = tid >> 6, lane = tid & 63;
  const int wm = wave >> 2, wn = wave & 3;
  const int lrow = lane & 15, lgrp = lane >> 4;
  const int dst = tid * 16;

  const char* pa[4] = {pa0, pa1, pa2, pa3};
  const char* pb[4] = {pb0, pb1, pb2, pb3};

  int offA[8][2], offB[4][2];
#pragma unroll
  for (int mi = 0; mi < 8; ++mi) {
    int rL = wm * 128 + mi * 16 + lrow;
#pragma unroll
    for (int ks = 0; ks < 2; ++ks)
      offA[mi][ks] = rL * 128 + (((ks * 4 + lgrp) + rL & 7) << 4);
  }
#pragma unroll
  for (int mi = 0; mi < 8; ++mi)
#pragma unroll
    for (int ks = 0; ks < 2; ++ks) {
      int rL = wm * 128 + mi * 16 + lrow;
      offA[mi][ks] = rL * 128 + ((((ks * 4 + lgrp) + rL) & 7) << 4);
    }
#pragma unroll
  for (int ni = 0; ni < 4; ++ni) {
    int rL = wn * 64 + ni * 16 + lrow;
#pragma unroll
    for (int ks = 0; ks < 2; ++ks)
      offB[ni][ks] = 32768 + rL * 128 + ((((ks * 4 + lgrp) + rL) & 7) << 4);
  }

  // prologue: stage kt0 -> buf0, kt1 -> buf1 (8 loads each; 16 outstanding)
#pragma unroll
  for (int g = 0; g < 4; ++g) { gload16(pa[g], smem + g * 8192 + dst); pa[g] += 128; }
#pragma unroll
  for (int g = 0; g < 4; ++g) { gload16(pb[g], smem + 32768 + g * 8192 + dst); pb[g] += 128; }
#pragma unroll
  for (int g = 0; g < 4; ++g) { gload16(pa[g], smem + 65536 + g * 8192 + dst); pa[g] += 128; }
#pragma unroll
  for (int g = 0; g < 4; ++g) { gload16(pb[g], smem + 65536 + 32768 + g * 8192 + dst); pb[g] += 128; }

  for (int kt = 0; kt < NKT; ++kt) {
    char* buf = smem + ((kt & 1) << 16);
    if (kt < NKT - 1) { VMWAIT(8); } else { VMWAIT(0); }
    __builtin_amdgcn_s_barrier();
    MEMFENCE;

    bf16x8 av[8], bv[4];
#pragma unroll
    for (int mi = 0; mi < 8; ++mi) av[mi] = *(const bf16x8*)(buf + offA[mi][0]);
#pragma unroll
    for (int ni = 0; ni < 4; ++ni) bv[ni] = *(const bf16x8*)(buf + offB[ni][0]);

    __builtin_amdgcn_s_setprio(1);
#pragma unroll
    for (int mi = 0; mi < 8; ++mi)
#pragma unroll
      for (int ni = 0; ni < 4; ++ni)
        acc[mi][ni] = __builtin_amdgcn_mfma_f32_16x16x32_bf16(
            av[mi], bv[ni], acc[mi][ni], 0, 0, 0);
    __builtin_amdgcn_s_setprio(0);

    bf16x8 av2[8], bv2[4];
#pragma unroll
    for (int mi = 0; mi < 8; ++mi) av2[mi] = *(const bf16x8*)(buf + offA[mi][1]);
#pragma unroll
    for (int ni = 0; ni < 4; ++ni) bv2[ni] = *(const bf16x8*)(buf + offB[ni][1]);

    asm volatile("s_waitcnt lgkmcnt(0)" ::: "memory");
    __builtin_amdgcn_s_barrier();   // all waves done reading buf -> safe to overwrite
    MEMFENCE;
    if (kt < NKT - 2) {
#pragma unroll
      for (int g = 0; g < 4; ++g) { gload16(pa[g], buf + g * 8192 + dst); pa[g] += 128; }
#pragma unroll
      for (int g = 0; g < 4; ++g) { gload16(pb[g], buf + 32768 + g * 8192 + dst); pb[g] += 128; }
    }
    __builtin_amdgcn_sched_barrier(0);
    __builtin_amdgcn_s_setprio(1);
#pragma unroll
    for (int mi = 0; mi < 8; ++mi)
#pragma unroll
      for (int ni = 0; ni < 4; ++ni)
        acc[mi][ni] = __builtin_amdgcn_mfma_f32_16x16x32_bf16(
            av2[mi], bv2[ni], acc[mi][ni], 0, 0, 0);
    __builtin_amdgcn_s_setprio(0);
  }
}

__device__ __forceinline__ float gelu_tanh(float v) {
  // tanh-form GELU; |err vs exact| <= ~3e-4 in h, negligible after GEMM2.
  float t = 0.7978845608028654f * (v + 0.044715f * v * v * v);
  float e = __expf(2.f * t);              // overflow -> inf -> tanh -> 1 (safe)
  float th = 1.f - 2.f / (e + 1.f);
  return 0.5f * v * (1.f + th);
}

__global__ __launch_bounds__(512, 2) void gemm1_kernel(
    const __hip_bfloat16* __restrict__ xb,
    const __hip_bfloat16* __restrict__ W1t,
    const float* __restrict__ b1,
    const int* __restrict__ IDX,
    __hip_bfloat16* __restrict__ h, int e0, int nblk) {
  __shared__ __align__(16) char smem[131072];
  int lin = blockIdx.x;
  { int q = nblk >> 3; lin = (lin & 7) * q + (lin >> 3); }  // XCD-contiguous
  const int tm = lin & 7, tn = (lin >> 3) & 15, ez = lin >> 7;
  const int e = e0 + ez;
  const int tid = threadIdx.x, wave = tid >> 6, lane = tid & 63;
  const int wm = wave >> 2, wn = wave & 3;
  const int lrow = lane & 15, lgrp = lane >> 4;

  const int r0 = tid >> 3;
  const int ksrc = (((tid & 7) - r0) & 7) * 16;  // inverse rotation on global src
  const char* pa[4]; const char* pb[4];
#pragma unroll
  for (int g = 0; g < 4; ++g) {
    int m = g * 64 + r0;
    int tok = IDX[e * CAP + tm * 256 + m];
    pa[g] = (const char*)(xb + (size_t)tok * DMODEL) + ksrc;
    int n = g * 64 + r0;
    pb[g] = (const char*)(W1t + ((size_t)e * DFF + tn * 256 + n) * DMODEL) + ksrc;
  }

  f32x4 acc[8][4];
  f32x4 zero = {0.f, 0.f, 0.f, 0.f};
#pragma unroll
  for (int mi = 0; mi < 8; ++mi)
#pragma unroll
    for (int ni = 0; ni < 4; ++ni) acc[mi][ni] = zero;

  gemm_core_v5<DMODEL / 64>(pa[0], pa[1], pa[2], pa[3],
                            pb[0], pb[1], pb[2], pb[3], smem, acc);

  __hip_bfloat16* he = h + (size_t)ez * CAP * DFF;
  const float* b1e = b1 + (size_t)e * DFF;
  float bvals[4];
#pragma unroll
  for (int ni = 0; ni < 4; ++ni)
    bvals[ni] = b1e[tn * 256 + wn * 64 + ni * 16 + lrow];
#pragma unroll
  for (int mi = 0; mi < 8; ++mi) {
#pragma unroll
    for (int j = 0; j < 4; ++j) {
      int row = tm * 256 + wm * 128 + mi * 16 + lgrp * 4 + j;
      __hip_bfloat16* hrow = he + (size_t)row * DFF;
#pragma unroll
      for (int ni = 0; ni < 4; ++ni) {
        int col = tn * 256 + wn * 64 + ni * 16 + lrow;
        float v = acc[mi][ni][j] + bvals[ni];
        hrow[col] = __float2bfloat16(gelu_tanh(v));
      }
    }
  }
}

__global__ __launch_bounds__(512, 2) void gemm2_kernel(
    const __hip_bfloat16* __restrict__ h,
    const __hip_bfloat16* __restrict__ W2t,
    const float* __restrict__ b2,
    const int* __restrict__ IDX, const float* __restrict__ G,
    float* __restrict__ out, int e0, int nblk) {
  __shared__ __align__(16) char smem[131072];
  int lin = blockIdx.x;
  { int q = nblk >> 3; lin = (lin & 7) * q + (lin >> 3); }
  const int tm = lin & 7, tn = (lin >> 3) & 3, ez = lin >> 5;
  const int e = e0 + ez;
  const int tid = threadIdx.x, wave = tid >> 6, lane = tid & 63;
  const int wm = wave >> 2, wn = wave & 3;
  const int lrow = lane & 15, lgrp = lane >> 4;

  const int r0 = tid >> 3;
  const int ksrc = (((tid & 7) - r0) & 7) * 16;
  const char* pa[4]; const char* pb[4];
#pragma unroll
  for (int g = 0; g < 4; ++g) {
    int m = g * 64 + r0;
    pa[g] = (const char*)(h + ((size_t)ez * CAP + tm * 256 + m) * DFF) + ksrc;
    int n = g * 64 + r0;
    pb[g] = (const char*)(W2t + ((size_t)e * DMODEL + tn * 256 + n) * DFF) + ksrc;
  }

  f32x4 acc[8][4];
  f32x4 zero = {0.f, 0.f, 0.f, 0.f};
#pragma unroll
  for (int mi = 0; mi < 8; ++mi)
#pragma unroll
    for (int ni = 0; ni < 4; ++ni) acc[mi][ni] = zero;

  gemm_core_v5<DFF / 64>(pa[0], pa[1], pa[2], pa[3],
                         pb[0], pb[1], pb[2], pb[3], smem, acc);

  const float* b2e = b2 + (size_t)e * DMODEL;
  const int* idxe = IDX + (size_t)e * CAP;
  const float* ge = G + (size_t)e * CAP;
  float bvals[4];
#pragma unroll
  for (int ni = 0; ni < 4; ++ni)
    bvals[ni] = b2e[tn * 256 + wn * 64 + ni * 16 + lrow];
#pragma unroll
  for (int mi = 0; mi < 8; ++mi) {
#pragma unroll
    for (int j = 0; j < 4; ++j) {
      int row = tm * 256 + wm * 128 + mi * 16 + lgrp * 4 + j;
      float g = ge[row];
      int tok = idxe[row];
      float* orow = out + (size_t)tok * DMODEL;
#pragma unroll
      for (int ni = 0; ni < 4; ++ni) {
        int col = tn * 256 + wn * 64 + ni * 16 + lrow;
        atomicAdd(orow + col, (acc[mi][ni][j] + bvals[ni]) * g);
      }
    }
  }
}

extern "C" void kernel_launch(void* const* d_in, const int* in_sizes, int n_in,
                              void* d_out, int out_size, void* d_ws, size_t ws_size,
                              hipStream_t stream) {
  const float* x  = (const float*)d_in[0];
  const float* Wr = (const float*)d_in[1];
  const float* W1 = (const float*)d_in[2];
  const float* b1 = (const float*)d_in[3];
  const float* W2 = (const float*)d_in[4];
  const float* b2 = (const float*)d_in[5];
  float* out = (float*)d_out;
  char* ws = (char*)d_ws;

  size_t off = 0;
  float* scoresT = (float*)(ws + off); off += (size_t)NEXP * NTOK * 4;
  float* G       = (float*)(ws + off); off += (size_t)NEXP * CAP * 4;
  int*   IDX     = (int*)(ws + off);   off += (size_t)NEXP * CAP * 4;
  __hip_bfloat16* xb  = (__hip_bfloat16*)(ws + off); off += (size_t)NTOK * DMODEL * 2;
  __hip_bfloat16* W1t = (__hip_bfloat16*)(ws + off); off += (size_t)NEXP * DFF * DMODEL * 2;
  __hip_bfloat16* W2t = (__hip_bfloat16*)(ws + off); off += (size_t)NEXP * DMODEL * DFF * 2;
  __hip_bfloat16* hbuf = (__hip_bfloat16*)(ws + off);
  size_t h_per_e = (size_t)CAP * DFF * 2;
  size_t avail = (ws_size > off) ? (ws_size - off) : 0;
  int EC = (int)(avail / h_per_e);
  if (EC < 1) EC = 1;
  if (EC > NEXP) EC = NEXP;

  zero_f32<<<512, 256, 0, stream>>>(out, out_size / 4);
  router_kernel<<<NTOK / 4, 256, 0, stream>>>(x, Wr, scoresT, xb);
  topk_kernel<<<NEXP, 256, 0, stream>>>(scoresT, G, IDX);
  transpose_cvt<<<dim3(DFF / 32, DMODEL / 32, NEXP), dim3(32, 8), 0, stream>>>(
      W1, W1t, DMODEL, DFF);
  transpose_cvt<<<dim3(DMODEL / 32, DFF / 32, NEXP), dim3(32, 8), 0, stream>>>(
      W2, W2t, DFF, DMODEL);
  for (int e0 = 0; e0 < NEXP; e0 += EC) {
    int ne = (NEXP - e0 < EC) ? (NEXP - e0) : EC;
    int nblk1 = 128 * ne;
    gemm1_kernel<<<nblk1, 512, 0, stream>>>(xb, W1t, b1, IDX, hbuf, e0, nblk1);
    int nblk2 = 32 * ne;
    gemm2_kernel<<<nblk2, 512, 0, stream>>>(hbuf, W2t, b2, IDX, G, out, e0, nblk2);
  }
}

// Round 6
// 472.240 us; speedup vs baseline: 1.1360x; 1.0073x over previous
//
#include <hip/hip_runtime.h>
#include <hip/hip_bf16.h>
#include <cstdint>
#include <cstddef>

#define NTOK 8192
#define DMODEL 1024
#define DFF 4096
#define NEXP 8
#define CAP 2048

typedef __attribute__((ext_vector_type(8))) __bf16 bf16x8;
typedef __attribute__((ext_vector_type(4))) float f32x4;

__device__ __forceinline__ void gload16(const void* g, void* l) {
  __builtin_amdgcn_global_load_lds(
      (__attribute__((address_space(1))) void*)(g),
      (__attribute__((address_space(3))) void*)(l),
      16, 0, 0);
}
#define VMWAIT_(n) asm volatile("s_waitcnt vmcnt(" #n ")" ::: "memory")
#define VMWAIT(n) VMWAIT_(n)
#define MEMFENCE asm volatile("" ::: "memory")

__global__ __launch_bounds__(256) void zero_f32(float* p, int n4) {
  int i = blockIdx.x * blockDim.x + threadIdx.x;
  int stride = gridDim.x * blockDim.x;
  float4 z = make_float4(0.f, 0.f, 0.f, 0.f);
  for (; i < n4; i += stride) ((float4*)p)[i] = z;
}

__global__ __launch_bounds__(256) void router_kernel(
    const float* __restrict__ x, const float* __restrict__ Wr,
    float* __restrict__ scoresT, __hip_bfloat16* __restrict__ xb) {
  const int lane = threadIdx.x & 63;
  const int t = blockIdx.x * 4 + (threadIdx.x >> 6);
  const float* xr = x + (size_t)t * DMODEL;
  float acc[NEXP];
#pragma unroll
  for (int j = 0; j < NEXP; ++j) acc[j] = 0.f;
#pragma unroll
  for (int it = 0; it < DMODEL / 64; ++it) {
    int d = it * 64 + lane;
    float xv = xr[d];
    xb[(size_t)t * DMODEL + d] = __float2bfloat16(xv);
    const float4* w = (const float4*)(Wr + (size_t)d * NEXP);
    float4 w0 = w[0], w1 = w[1];
    acc[0] += xv * w0.x; acc[1] += xv * w0.y; acc[2] += xv * w0.z; acc[3] += xv * w0.w;
    acc[4] += xv * w1.x; acc[5] += xv * w1.y; acc[6] += xv * w1.z; acc[7] += xv * w1.w;
  }
#pragma unroll
  for (int off = 32; off; off >>= 1) {
#pragma unroll
    for (int j = 0; j < NEXP; ++j) acc[j] += __shfl_xor(acc[j], off);
  }
  float m = acc[0];
#pragma unroll
  for (int j = 1; j < NEXP; ++j) m = fmaxf(m, acc[j]);
  float s = 0.f;
#pragma unroll
  for (int j = 0; j < NEXP; ++j) { acc[j] = expf(acc[j] - m); s += acc[j]; }
  float inv = 1.f / s;
  if (lane < NEXP) scoresT[(size_t)lane * NTOK + t] = acc[lane] * inv;
}

__global__ __launch_bounds__(256) void topk_kernel(
    const float* __restrict__ scoresT, float* __restrict__ G, int* __restrict__ IDX) {
  __shared__ uint32_t sb[NTOK];
  __shared__ uint32_t hist[256];
  __shared__ uint32_t s_prefix, s_rem;
  __shared__ uint32_t eq_list[256];
  __shared__ uint32_t eq_cnt, gt_cnt;
  const int e = blockIdx.x, tid = threadIdx.x;
  const float* se = scoresT + (size_t)e * NTOK;
  for (int i = tid; i < NTOK; i += 256) sb[i] = __float_as_uint(se[i]);
  if (tid == 0) { s_prefix = 0u; s_rem = CAP; eq_cnt = 0u; gt_cnt = 0u; }
  __syncthreads();
  for (int r = 0; r < 4; ++r) {
    const int shift = 24 - 8 * r;
    for (int i = tid; i < 256; i += 256) hist[i] = 0u;
    __syncthreads();
    uint32_t pfx = s_prefix;
    for (int i = tid; i < NTOK; i += 256) {
      uint32_t b = sb[i];
      if (((b >> shift) >> 8) == pfx) atomicAdd(&hist[(b >> shift) & 255u], 1u);
    }
    __syncthreads();
    if (tid == 0) {
      uint32_t rem = s_rem, cum = 0u;
      int d = 255;
      for (; d > 0; --d) {
        if (cum + hist[d] >= rem) break;
        cum += hist[d];
      }
      s_prefix = (pfx << 8) | (uint32_t)d;
      s_rem = rem - cum;
    }
    __syncthreads();
  }
  const uint32_t T = s_prefix, need = s_rem;
  for (int i = tid; i < NTOK; i += 256) {
    uint32_t b = sb[i];
    if (b > T) {
      uint32_t p = atomicAdd(&gt_cnt, 1u);
      IDX[(size_t)e * CAP + p] = i;
      G[(size_t)e * CAP + p] = __uint_as_float(b);
    } else if (b == T) {
      uint32_t c = atomicAdd(&eq_cnt, 1u);
      if (c < 256u) eq_list[c] = (uint32_t)i;
    }
  }
  __syncthreads();
  if (tid == 0) {
    uint32_t base = gt_cnt;
    uint32_t c = eq_cnt < 256u ? eq_cnt : 256u;
    for (uint32_t s = 0; s < need; ++s) {
      uint32_t mv = 0xFFFFFFFFu; int mi = 0;
      for (uint32_t j = 0; j < c; ++j)
        if (eq_list[j] < mv) { mv = eq_list[j]; mi = (int)j; }
      eq_list[mi] = 0xFFFFFFFFu;
      IDX[(size_t)e * CAP + base + s] = (int)mv;
      G[(size_t)e * CAP + base + s] = __uint_as_float(T);
    }
  }
}

__global__ __launch_bounds__(256) void transpose_cvt(
    const float* __restrict__ in, __hip_bfloat16* __restrict__ out, int R, int C) {
  __shared__ float tile[32][33];
  const int e = blockIdx.z;
  const float* ine = in + (size_t)e * R * C;
  __hip_bfloat16* oute = out + (size_t)e * R * C;
  const int c0 = blockIdx.x * 32, r0 = blockIdx.y * 32;
  const int tx = threadIdx.x, ty = threadIdx.y;
#pragma unroll
  for (int i = 0; i < 4; ++i)
    tile[ty + i * 8][tx] = ine[(size_t)(r0 + ty + i * 8) * C + (c0 + tx)];
  __syncthreads();
#pragma unroll
  for (int i = 0; i < 4; ++i)
    oute[(size_t)(c0 + ty + i * 8) * R + (r0 + tx)] =
        __float2bfloat16(tile[tx][ty + i * 8]);
}

// ===== 256x256, BK=64, m201-faithful 8-phase / 2-K-tile pipeline =====
// LDS 128 KiB: buf d (d=kt&1) at d*65536: A halves h*16384, B at +32768+h*16384.
// Half = 128 rows x 64 k (16 KB). Row rL: logical 16B slot s at phys (s+rL)&7;
// global source pre-rotated inversely (G21). 8 waves (2m x 4n), wave tile 128x64,
// acc[8][4]. Per phase: quadrant ds_reads; stage ONE half (2 gload_lds); bar;
// lgkmcnt(0)+sched_barrier; setprio(1); 16 MFMA; setprio(0); bar.
// Stage schedule per iter i (kt0=2i in buf0, kt1=2i+1 in buf1):
//  ph1: A(2i+1)h0->b1  ph2: A(2i+1)h1->b1  ph3: B(2i+2)h0->b0  ph4: B(2i+2)h1->b0
//  ph5: A(2i+2)h0->b0  ph6: A(2i+2)h1->b0  ph7: B(2i+3)h0->b1  ph8: B(2i+3)h1->b1
// vmcnt(4) only at end of ph4/ph8 (exactly the 2 not-yet-needed halves remain
// in flight); tail iterations drain with vmcnt(0) once.

#define RD_A(BASE, H)                                                          \
  {                                                                            \
    _Pragma("unroll") for (int mi = 0; mi < 4; ++mi)                           \
        _Pragma("unroll") for (int ks = 0; ks < 2; ++ks) av[mi][ks] =          \
        *(const bf16x8*)((BASE) + Ab + offA[(H)*4 + mi][ks]);                  \
  }
#define RD_B(BASE, BV, H2)                                                     \
  {                                                                            \
    _Pragma("unroll") for (int ni = 0; ni < 2; ++ni)                           \
        _Pragma("unroll") for (int ks = 0; ks < 2; ++ks) BV[ni][ks] =          \
        *(const bf16x8*)((BASE) + Bb + offB[(H2)*2 + ni][ks]);                 \
  }
#define STAGE_A(H, BUF)                                                        \
  {                                                                            \
    gload16(pa[(H)*2], (BUF) + (H)*16384 + dst);                               \
    pa[(H)*2] += 128;                                                          \
    gload16(pa[(H)*2 + 1], (BUF) + (H)*16384 + 8192 + dst);                    \
    pa[(H)*2 + 1] += 128;                                                      \
  }
#define STAGE_B(H, BUF)                                                        \
  {                                                                            \
    gload16(pb[(H)*2], (BUF) + 32768 + (H)*16384 + dst);                       \
    pb[(H)*2] += 128;                                                          \
    gload16(pb[(H)*2 + 1], (BUF) + 32768 + (H)*16384 + 8192 + dst);            \
    pb[(H)*2 + 1] += 128;                                                      \
  }
#define PH_PRE                                                                 \
  __builtin_amdgcn_s_barrier();                                                \
  MEMFENCE;                                                                    \
  asm volatile("s_waitcnt lgkmcnt(0)" ::: "memory");                           \
  __builtin_amdgcn_sched_barrier(0);                                           \
  __builtin_amdgcn_s_setprio(1);
#define PH_POST                                                                \
  __builtin_amdgcn_s_setprio(0);                                               \
  __builtin_amdgcn_s_barrier();                                                \
  MEMFENCE;
#define MFMA_Q(MB, NB, BV)                                                     \
  {                                                                            \
    _Pragma("unroll") for (int mi = 0; mi < 4; ++mi)                           \
        _Pragma("unroll") for (int ni = 0; ni < 2; ++ni)                       \
            _Pragma("unroll") for (int ks = 0; ks < 2; ++ks)                   \
                acc[(MB) + mi][(NB) + ni] =                                    \
        __builtin_amdgcn_mfma_f32_16x16x32_bf16(                               \
            av[mi][ks], BV[ni][ks], acc[(MB) + mi][(NB) + ni], 0, 0, 0);       \
  }

template <int NKT>
__device__ __forceinline__ void gemm_core8(
    const char* pa0, const char* pa1, const char* pa2, const char* pa3,
    const char* pb0, const char* pb1, const char* pb2, const char* pb3,
    char* smem, f32x4 (&acc)[8][4]) {
  const int tid = threadIdx.x;
  const int wave = tid >> 6, lane = tid & 63;
  const int wm = wave >> 2, wn = wave & 3;
  const int lrow = lane & 15, lgrp = lane >> 4;
  const int dst = tid * 16;

  const char* pa[4] = {pa0, pa1, pa2, pa3};
  const char* pb[4] = {pb0, pb1, pb2, pb3};

  int offA[8][2], offB[4][2];
#pragma unroll
  for (int mi = 0; mi < 8; ++mi) {
    int rL = mi * 16 + lrow;
#pragma unroll
    for (int ks = 0; ks < 2; ++ks)
      offA[mi][ks] = rL * 128 + ((((ks * 4 + lgrp) + rL) & 7) << 4);
  }
#pragma unroll
  for (int ni = 0; ni < 4; ++ni) {
    int rL = (wn & 1) * 64 + ni * 16 + lrow;
#pragma unroll
    for (int ks = 0; ks < 2; ++ks)
      offB[ni][ks] = rL * 128 + ((((ks * 4 + lgrp) + rL) & 7) << 4);
  }
  const int Ab = wm * 16384;
  const int Bb = 32768 + (wn >> 1) * 16384;

  char* b0 = smem;
  char* b1 = smem + 65536;

  // prologue: buf0 <- kt0 (A h0,h1 + B h0,h1), buf1 <- kt1 B halves
#pragma unroll
  for (int g = 0; g < 4; ++g) {
    gload16(pa[g], b0 + (g >> 1) * 16384 + (g & 1) * 8192 + dst);
    pa[g] += 128;
  }
#pragma unroll
  for (int g = 0; g < 4; ++g) {
    gload16(pb[g], b0 + 32768 + (g >> 1) * 16384 + (g & 1) * 8192 + dst);
    pb[g] += 128;
  }
#pragma unroll
  for (int g = 0; g < 4; ++g) {
    gload16(pb[g], b1 + 32768 + (g >> 1) * 16384 + (g & 1) * 8192 + dst);
    pb[g] += 128;
  }
  VMWAIT(4);
  __builtin_amdgcn_s_barrier();
  MEMFENCE;

  bf16x8 av[4][2], bv0[2][2], bv1[2][2];

  for (int i = 0; i < NKT / 2; ++i) {
    const bool st2 = (2 * i + 2 < NKT);
    const bool st3 = (2 * i + 3 < NKT);

    // ---- phase 1: q(m0,n0) of kt0
    RD_A(b0, 0); RD_B(b0, bv0, 0);
    STAGE_A(0, b1);
    PH_PRE; MFMA_Q(0, 0, bv0); PH_POST;
    // ---- phase 2: q(m0,n1)
    RD_B(b0, bv1, 1);
    STAGE_A(1, b1);
    PH_PRE; MFMA_Q(0, 2, bv1); PH_POST;
    // ---- phase 3: q(m1,n1)
    RD_A(b0, 1);
    if (st2) STAGE_B(0, b0);
    PH_PRE; MFMA_Q(4, 2, bv1); PH_POST;
    // ---- phase 4: q(m1,n0)  [gate for kt1 reads]
    if (st2) STAGE_B(1, b0);
    PH_PRE; MFMA_Q(4, 0, bv0);
    __builtin_amdgcn_s_setprio(0);
    if (st2) { VMWAIT(4); } else { VMWAIT(0); }
    __builtin_amdgcn_s_barrier();
    MEMFENCE;

    // ---- phase 5: q(m0,n0) of kt1
    RD_A(b1, 0); RD_B(b1, bv0, 0);
    if (st2) STAGE_A(0, b0);
    PH_PRE; MFMA_Q(0, 0, bv0); PH_POST;
    // ---- phase 6: q(m0,n1)
    RD_B(b1, bv1, 1);
    if (st2) STAGE_A(1, b0);
    PH_PRE; MFMA_Q(0, 2, bv1); PH_POST;
    // ---- phase 7: q(m1,n1)
    RD_A(b1, 1);
    if (st3) STAGE_B(0, b1);
    PH_PRE; MFMA_Q(4, 2, bv1); PH_POST;
    // ---- phase 8: q(m1,n0)  [gate for next-iter kt0 reads]
    if (st3) STAGE_B(1, b1);
    PH_PRE; MFMA_Q(4, 0, bv0);
    __builtin_amdgcn_s_setprio(0);
    if (st3) { VMWAIT(4); }
    __builtin_amdgcn_s_barrier();
    MEMFENCE;
  }
}

__device__ __forceinline__ float gelu_tanh(float v) {
  float t = 0.7978845608028654f * (v + 0.044715f * v * v * v);
  float e = __expf(2.f * t);
  float th = 1.f - 2.f / (e + 1.f);
  return 0.5f * v * (1.f + th);
}

__global__ __launch_bounds__(512, 2) void gemm1_kernel(
    const __hip_bfloat16* __restrict__ xb,
    const __hip_bfloat16* __restrict__ W1t,
    const float* __restrict__ b1,
    const int* __restrict__ IDX,
    __hip_bfloat16* __restrict__ h, int e0, int nblk) {
  __shared__ __align__(16) char smem[131072];
  int lin = blockIdx.x;
  { int q = nblk >> 3; lin = (lin & 7) * q + (lin >> 3); }  // XCD-contiguous
  const int tm = lin & 7, tn = (lin >> 3) & 15, ez = lin >> 7;
  const int e = e0 + ez;
  const int tid = threadIdx.x, wave = tid >> 6, lane = tid & 63;
  const int wm = wave >> 2, wn = wave & 3;
  const int lrow = lane & 15, lgrp = lane >> 4;

  const int r0 = tid >> 3;
  const int ksrc = (((tid & 7) - r0) & 7) * 16;  // inverse rotation on global src
  const char* pa[4]; const char* pb[4];
#pragma unroll
  for (int g = 0; g < 4; ++g) {
    int m = g * 64 + r0;
    int tok = IDX[e * CAP + tm * 256 + m];
    pa[g] = (const char*)(xb + (size_t)tok * DMODEL) + ksrc;
    int n = g * 64 + r0;
    pb[g] = (const char*)(W1t + ((size_t)e * DFF + tn * 256 + n) * DMODEL) + ksrc;
  }

  f32x4 acc[8][4];
  f32x4 zero = {0.f, 0.f, 0.f, 0.f};
#pragma unroll
  for (int mi = 0; mi < 8; ++mi)
#pragma unroll
    for (int ni = 0; ni < 4; ++ni) acc[mi][ni] = zero;

  gemm_core8<DMODEL / 64>(pa[0], pa[1], pa[2], pa[3],
                          pb[0], pb[1], pb[2], pb[3], smem, acc);

  __hip_bfloat16* he = h + (size_t)ez * CAP * DFF;
  const float* b1e = b1 + (size_t)e * DFF;
  float bvals[4];
#pragma unroll
  for (int ni = 0; ni < 4; ++ni)
    bvals[ni] = b1e[tn * 256 + wn * 64 + ni * 16 + lrow];
#pragma unroll
  for (int mi = 0; mi < 8; ++mi) {
#pragma unroll
    for (int j = 0; j < 4; ++j) {
      int row = tm * 256 + wm * 128 + mi * 16 + lgrp * 4 + j;
      __hip_bfloat16* hrow = he + (size_t)row * DFF;
#pragma unroll
      for (int ni = 0; ni < 4; ++ni) {
        int col = tn * 256 + wn * 64 + ni * 16 + lrow;
        float v = acc[mi][ni][j] + bvals[ni];
        hrow[col] = __float2bfloat16(gelu_tanh(v));
      }
    }
  }
}

__global__ __launch_bounds__(512, 2) void gemm2_kernel(
    const __hip_bfloat16* __restrict__ h,
    const __hip_bfloat16* __restrict__ W2t,
    const float* __restrict__ b2,
    const int* __restrict__ IDX, const float* __restrict__ G,
    float* __restrict__ out, int e0, int nblk) {
  __shared__ __align__(16) char smem[131072];
  int lin = blockIdx.x;
  { int q = nblk >> 3; lin = (lin & 7) * q + (lin >> 3); }
  const int tm = lin & 7, tn = (lin >> 3) & 3, ez = lin >> 5;
  const int e = e0 + ez;
  const int tid = threadIdx.x, wave = tid >> 6, lane = tid & 63;
  const int wm = wave >> 2, wn = wave & 3;
  const int lrow = lane & 15, lgrp = lane >> 4;

  const int r0 = tid >> 3;
  const int ksrc = (((tid & 7) - r0) & 7) * 16;
  const char* pa[4]; const char* pb[4];
#pragma unroll
  for (int g = 0; g < 4; ++g) {
    int m = g * 64 + r0;
    pa[g] = (const char*)(h + ((size_t)ez * CAP + tm * 256 + m) * DFF) + ksrc;
    int n = g * 64 + r0;
    pb[g] = (const char*)(W2t + ((size_t)e * DMODEL + tn * 256 + n) * DFF) + ksrc;
  }

  f32x4 acc[8][4];
  f32x4 zero = {0.f, 0.f, 0.f, 0.f};
#pragma unroll
  for (int mi = 0; mi < 8; ++mi)
#pragma unroll
    for (int ni = 0; ni < 4; ++ni) acc[mi][ni] = zero;

  gemm_core8<DFF / 64>(pa[0], pa[1], pa[2], pa[3],
                       pb[0], pb[1], pb[2], pb[3], smem, acc);

  const float* b2e = b2 + (size_t)e * DMODEL;
  const int* idxe = IDX + (size_t)e * CAP;
  const float* ge = G + (size_t)e * CAP;
  float bvals[4];
#pragma unroll
  for (int ni = 0; ni < 4; ++ni)
    bvals[ni] = b2e[tn * 256 + wn * 64 + ni * 16 + lrow];
#pragma unroll
  for (int mi = 0; mi < 8; ++mi) {
#pragma unroll
    for (int j = 0; j < 4; ++j) {
      int row = tm * 256 + wm * 128 + mi * 16 + lgrp * 4 + j;
      float g = ge[row];
      int tok = idxe[row];
      float* orow = out + (size_t)tok * DMODEL;
#pragma unroll
      for (int ni = 0; ni < 4; ++ni) {
        int col = tn * 256 + wn * 64 + ni * 16 + lrow;
        atomicAdd(orow + col, (acc[mi][ni][j] + bvals[ni]) * g);
      }
    }
  }
}

extern "C" void kernel_launch(void* const* d_in, const int* in_sizes, int n_in,
                              void* d_out, int out_size, void* d_ws, size_t ws_size,
                              hipStream_t stream) {
  const float* x  = (const float*)d_in[0];
  const float* Wr = (const float*)d_in[1];
  const float* W1 = (const float*)d_in[2];
  const float* b1 = (const float*)d_in[3];
  const float* W2 = (const float*)d_in[4];
  const float* b2 = (const float*)d_in[5];
  float* out = (float*)d_out;
  char* ws = (char*)d_ws;

  size_t off = 0;
  float* scoresT = (float*)(ws + off); off += (size_t)NEXP * NTOK * 4;
  float* G       = (float*)(ws + off); off += (size_t)NEXP * CAP * 4;
  int*   IDX     = (int*)(ws + off);   off += (size_t)NEXP * CAP * 4;
  __hip_bfloat16* xb  = (__hip_bfloat16*)(ws + off); off += (size_t)NTOK * DMODEL * 2;
  __hip_bfloat16* W1t = (__hip_bfloat16*)(ws + off); off += (size_t)NEXP * DFF * DMODEL * 2;
  __hip_bfloat16* W2t = (__hip_bfloat16*)(ws + off); off += (size_t)NEXP * DMODEL * DFF * 2;
  __hip_bfloat16* hbuf = (__hip_bfloat16*)(ws + off);
  size_t h_per_e = (size_t)CAP * DFF * 2;
  size_t avail = (ws_size > off) ? (ws_size - off) : 0;
  int EC = (int)(avail / h_per_e);
  if (EC < 1) EC = 1;
  if (EC > NEXP) EC = NEXP;

  zero_f32<<<512, 256, 0, stream>>>(out, out_size / 4);
  router_kernel<<<NTOK / 4, 256, 0, stream>>>(x, Wr, scoresT, xb);
  topk_kernel<<<NEXP, 256, 0, stream>>>(scoresT, G, IDX);
  transpose_cvt<<<dim3(DFF / 32, DMODEL / 32, NEXP), dim3(32, 8), 0, stream>>>(
      W1, W1t, DMODEL, DFF);
  transpose_cvt<<<dim3(DMODEL / 32, DFF / 32, NEXP), dim3(32, 8), 0, stream>>>(
      W2, W2t, DFF, DMODEL);
  for (int e0 = 0; e0 < NEXP; e0 += EC) {
    int ne = (NEXP - e0 < EC) ? (NEXP - e0) : EC;
    int nblk1 = 128 * ne;
    gemm1_kernel<<<nblk1, 512, 0, stream>>>(xb, W1t, b1, IDX, hbuf, e0, nblk1);
    int nblk2 = 32 * ne;
    gemm2_kernel<<<nblk2, 512, 0, stream>>>(hbuf, W2t, b2, IDX, G, out, e0, nblk2);
  }
}